// Round 6
// baseline (300.559 us; speedup 1.0000x reference)
//
#include <hip/hip_runtime.h>

typedef __attribute__((ext_vector_type(8))) short short8;
typedef __attribute__((ext_vector_type(4))) short short4v;
typedef __attribute__((ext_vector_type(4))) float f32x4;

#define DEVI static __device__ __forceinline__

constexpr int NB   = 4;     // batch
constexpr int NH   = 2;     // heads
constexpr int SEQ  = 2048;  // Lq = Lk
constexpr int DM   = 512;   // d_model
constexpr int DKV  = 64;    // d_k = d_v
constexpr int HDIM = 128;   // NH * DKV

DEVI unsigned short f2bf(float f) {
    union { float f; unsigned u; } v; v.f = f;
    unsigned r = v.u + 0x7FFFu + ((v.u >> 16) & 1u);
    return (unsigned short)(r >> 16);
}
DEVI float bf2f(unsigned short s) {
    union { unsigned u; float f; } v; v.u = ((unsigned)s) << 16; return v.f;
}
DEVI unsigned pk2(float a, float b) {
    return (unsigned)f2bf(a) | ((unsigned)f2bf(b) << 16);
}
// async global->LDS, 16B per lane. LDS dest = wave-uniform base + lane*16.
DEVI void async16(const void* g, void* l) {
    __builtin_amdgcn_global_load_lds(
        (const __attribute__((address_space(1))) unsigned int*)g,
        (__attribute__((address_space(3))) unsigned int*)l, 16, 0, 0);
}

// ---------------------------------------------------------------------------
// k_prep: weights f32 -> bf16 transposed, via LDS tile transpose. (r4 version)
__global__ __launch_bounds__(256) void k_prep(
    const float* __restrict__ Wq, const float* __restrict__ Wk,
    const float* __restrict__ Wv, const float* __restrict__ Wo,
    unsigned short* __restrict__ Wqt, unsigned short* __restrict__ Wkt,
    unsigned short* __restrict__ Wvt, unsigned short* __restrict__ Wot) {
    __shared__ unsigned short T[64][72];          // +8 pad
    const int bid = blockIdx.x, tid = threadIdx.x;
    const float* src; unsigned short* dst; int ss, ds, k0, n0;
    if (bid < 48) {                               // W[512k][128n] -> Wt[128n][512k]
        int m = bid >> 4, t16 = bid & 15;
        src = m == 0 ? Wq : (m == 1 ? Wk : Wv);
        dst = m == 0 ? Wqt : (m == 1 ? Wkt : Wvt);
        ss = 128; ds = 512;
        k0 = (t16 >> 1) * 64; n0 = (t16 & 1) * 64;
    } else {                                      // Wo[128k][512n] -> Wot[512n][128k]
        int t16 = bid - 48;
        src = Wo; dst = Wot; ss = 512; ds = 128;
        k0 = (t16 >> 3) * 64; n0 = (t16 & 7) * 64;
    }
    const int kk = tid >> 4, nn4 = (tid & 15) * 4;
    #pragma unroll
    for (int i = 0; i < 4; ++i) {
        float4 v = *(const float4*)(src + (size_t)(k0 + kk + i * 16) * ss + n0 + nn4);
        T[kk + i * 16][nn4]     = f2bf(v.x);
        T[kk + i * 16][nn4 + 1] = f2bf(v.y);
        T[kk + i * 16][nn4 + 2] = f2bf(v.z);
        T[kk + i * 16][nn4 + 3] = f2bf(v.w);
    }
    __syncthreads();
    const int nn = tid >> 2, kc = (tid & 3) * 16;
    unsigned short tmp[16];
    #pragma unroll
    for (int i = 0; i < 16; ++i) tmp[i] = T[kc + i][nn];
    unsigned short* o = dst + (size_t)(n0 + nn) * ds + k0 + kc;
    *(uint4*)o       = *(uint4*)tmp;
    *(uint4*)(o + 8) = *(uint4*)(tmp + 8);
}

// ---------------------------------------------------------------------------
// k_proj: X[8192,512] @ W[512,128] + b  ->  per-head bf16 layouts. (r0 proven)
__global__ __launch_bounds__(256) void k_proj(
    const float* __restrict__ Qg, const float* __restrict__ Kg, const float* __restrict__ Vg,
    const unsigned short* __restrict__ Wqt, const unsigned short* __restrict__ Wkt,
    const unsigned short* __restrict__ Wvt,
    const float* __restrict__ bq, const float* __restrict__ bk, const float* __restrict__ bv,
    unsigned short* __restrict__ qs, unsigned short* __restrict__ kb,
    unsigned short* __restrict__ vt) {
    __shared__ unsigned short lA[64 * 64];
    __shared__ unsigned short lB[128 * 64];

    const int y = blockIdx.y;
    const float* X = y == 0 ? Qg : (y == 1 ? Kg : Vg);
    const unsigned short* Wt = y == 0 ? Wqt : (y == 1 ? Wkt : Wvt);
    const float* bias = y == 0 ? bq : (y == 1 ? bk : bv);
    const float scal = y == 0 ? 0.125f : 1.0f;   // fold 1/sqrt(dk) into q
    const int row0 = blockIdx.x * 64;
    const int tid = threadIdx.x, lane = tid & 63, wv = tid >> 6;
    const int l16 = lane & 15, lq4 = lane >> 4;
    const int wr = wv >> 1, wc = wv & 1;

    f32x4 acc[2][4];
    #pragma unroll
    for (int i = 0; i < 2; ++i)
        #pragma unroll
        for (int j = 0; j < 4; ++j) acc[i][j] = f32x4{0.f, 0.f, 0.f, 0.f};

    const int arow = tid >> 2, ac0 = (tid & 3) * 16;

    for (int kc = 0; kc < 8; ++kc) {
        {
            const float* src = X + (size_t)(row0 + arow) * DM + kc * 64 + ac0;
            unsigned short* dst = &lA[arow * 64 + ac0];
            #pragma unroll
            for (int i = 0; i < 4; ++i) {
                float4 v = *(const float4*)(src + 4 * i);
                unsigned p0 = (unsigned)f2bf(v.x) | ((unsigned)f2bf(v.y) << 16);
                unsigned p1 = (unsigned)f2bf(v.z) | ((unsigned)f2bf(v.w) << 16);
                *(unsigned*)(dst + 4 * i) = p0;
                *(unsigned*)(dst + 4 * i + 2) = p1;
            }
        }
        #pragma unroll
        for (int c = 0; c < 4; ++c) {
            int chunk = wv * 4 + c;
            int n = chunk * 8 + (lane >> 3);
            int kpart = (lane & 7) * 8;
            const void* g = (const char*)Wt + ((size_t)n * DM + kc * 64 + kpart) * 2;
            void* l = (char*)lB + chunk * 1024 + lane * 16;
            async16(g, l);
        }
        __syncthreads();

        #pragma unroll
        for (int ks = 0; ks < 2; ++ks) {
            short8 a[2], b[4];
            #pragma unroll
            for (int mt = 0; mt < 2; ++mt) {
                int m = wr * 32 + mt * 16 + l16;
                a[mt] = *(const short8*)&lA[m * 64 + ks * 32 + lq4 * 8];
            }
            #pragma unroll
            for (int nt = 0; nt < 4; ++nt) {
                int n = wc * 64 + nt * 16 + l16;
                b[nt] = *(const short8*)&lB[n * 64 + ks * 32 + lq4 * 8];
            }
            #pragma unroll
            for (int mt = 0; mt < 2; ++mt)
                #pragma unroll
                for (int nt = 0; nt < 4; ++nt)
                    acc[mt][nt] = __builtin_amdgcn_mfma_f32_16x16x32_bf16(
                        a[mt], b[nt], acc[mt][nt], 0, 0, 0);
        }
        __syncthreads();
    }

    if (y < 2) {
        unsigned short* dstp = (y == 0) ? qs : kb;
        #pragma unroll
        for (int mt = 0; mt < 2; ++mt)
            #pragma unroll
            for (int nt = 0; nt < 4; ++nt) {
                int col = wc * 64 + nt * 16 + l16;
                float bb = bias[col];
                int h = col >> 6, d = col & 63;
                #pragma unroll
                for (int r = 0; r < 4; ++r) {
                    int row = row0 + wr * 32 + mt * 16 + lq4 * 4 + r;
                    int b = row >> 11, pos = row & 2047;
                    float val = (acc[mt][nt][r] + bb) * scal;
                    dstp[((size_t)(b * NH + h) * SEQ + pos) * DKV + d] = f2bf(val);
                }
            }
    } else {
        #pragma unroll
        for (int mt = 0; mt < 2; ++mt)
            #pragma unroll
            for (int nt = 0; nt < 4; ++nt) {
                int col = wc * 64 + nt * 16 + l16;
                float bb = bias[col];
                #pragma unroll
                for (int r = 0; r < 4; ++r) {
                    int mrow = wr * 32 + mt * 16 + lq4 * 4 + r;
                    lB[col * 64 + mrow] = f2bf(acc[mt][nt][r] + bb);
                }
            }
        __syncthreads();
        int c = tid >> 1, mp = (tid & 1) * 32;
        int b = row0 >> 11, kpos0 = row0 & 2047;
        int h = c >> 6, d = c & 63;
        unsigned short* dst = vt + ((size_t)(b * NH + h) * DKV + d) * SEQ + kpos0 + mp;
        const unsigned short* srcl = &lB[c * 64 + mp];
        #pragma unroll
        for (int i = 0; i < 4; ++i)
            *(uint4*)(dst + 8 * i) = *(const uint4*)(srcl + 8 * i);
    }
}

// ---------------------------------------------------------------------------
// k_attn: ONE QK pass per (bh, q-tile64, k-quarter).
//   s = masked 10*tanh(qk/8)  (raw, bf16) -> lAttn -> sg global (67 MB)
//   sums = sum_k exp(s)       -> Lpart[ksp]          (pass1's epilogue)
//   o    = sum_k s*v  (RAW)   -> outh2[ksp]          (identity: -L*Vsum later)
//   qt==0 blocks also reduce their staged V tiles -> vsumPart[ksp][bh][d].
// No second QK^T pass anywhere. K + mask direct from L2; V async16 staged.
__global__ __launch_bounds__(256) void k_attn(
    const unsigned short* __restrict__ qs, const unsigned short* __restrict__ kb,
    const unsigned short* __restrict__ vt, const int* __restrict__ maskg,
    unsigned short* __restrict__ sg, float* __restrict__ Lpart,
    float* __restrict__ vsumPart, float* __restrict__ outh2) {
    __shared__ unsigned short lV[64 * 128];      // v^T tile [d][kpos]
    __shared__ unsigned short lAttn[64 * 136];   // raw-s tile [q][kpos], +8 pad
    __shared__ float lsumW[4 * 64];

    const int bx = blockIdx.x;
    const int bh = bx & 7;                        // XCD-pinned
    const int qt = (bx >> 3) & 31;
    const int ksp = bx >> 8;
    const int qbase = qt * 64;
    const int b = bh >> 1, h = bh & 1;
    const int tid = threadIdx.x, lane = tid & 63, wv = tid >> 6;
    const int l16 = lane & 15, lq4 = lane >> 4;

    short8 aq[4][2];
    #pragma unroll
    for (int mt = 0; mt < 4; ++mt)
        #pragma unroll
        for (int ks = 0; ks < 2; ++ks) {
            size_t off = ((size_t)bh * SEQ + qbase + mt * 16 + l16) * DKV + ks * 32 + lq4 * 8;
            aq[mt][ks] = *(const short8*)(qs + off);
        }

    float sums[4][4];
    #pragma unroll
    for (int mt = 0; mt < 4; ++mt)
        #pragma unroll
        for (int r = 0; r < 4; ++r) sums[mt][r] = 0.f;

    f32x4 o[4];
    #pragma unroll
    for (int mt = 0; mt < 4; ++mt) o[mt] = f32x4{0.f, 0.f, 0.f, 0.f};

    float vsum_acc = 0.f;

    const unsigned short* kB = kb + (size_t)bh * SEQ * DKV;
    const int* mB = maskg + b * SEQ;

    for (int kt = 0; kt < 4; ++kt) {
        const int kbase = ksp * 512 + kt * 128;

        // stage V(kt) early: latency hides under QK + score phase
        #pragma unroll
        for (int c = 0; c < 4; ++c) {
            int chunk = wv * 4 + c;
            int d = chunk * 4 + (lane >> 4);
            int kk = (lane & 15) * 8;
            const void* g = (const char*)vt + (((size_t)bh * DKV + d) * SEQ + kbase + kk) * 2;
            void* l = (char*)lV + chunk * 1024 + lane * 16;
            async16(g, l);
        }

        // QK: K frags + mask direct from L2
        short8 bfr[2][2];
        int mv[2];
        #pragma unroll
        for (int nt = 0; nt < 2; ++nt) {
            int n = kbase + wv * 32 + nt * 16 + l16;
            const unsigned short* p = kB + (size_t)n * DKV + lq4 * 8;
            bfr[0][nt] = *(const short8*)p;
            bfr[1][nt] = *(const short8*)(p + 32);
            mv[nt] = mB[n];
        }
        f32x4 s[4][2];
        #pragma unroll
        for (int mt = 0; mt < 4; ++mt)
            #pragma unroll
            for (int nt = 0; nt < 2; ++nt) s[mt][nt] = f32x4{0.f, 0.f, 0.f, 0.f};
        #pragma unroll
        for (int ks = 0; ks < 2; ++ks)
            #pragma unroll
            for (int mt = 0; mt < 4; ++mt)
                #pragma unroll
                for (int nt = 0; nt < 2; ++nt)
                    s[mt][nt] = __builtin_amdgcn_mfma_f32_16x16x32_bf16(
                        aq[mt][ks], bfr[ks][nt], s[mt][nt], 0, 0, 0);

        // raw s -> LDS (bf16) + exp-sums
        #pragma unroll
        for (int nt = 0; nt < 2; ++nt) {
            int col = wv * 32 + nt * 16 + l16;
            int m_ = mv[nt];
            #pragma unroll
            for (int mt = 0; mt < 4; ++mt)
                #pragma unroll
                for (int r = 0; r < 4; ++r) {
                    float x = s[mt][nt][r];
                    float e2 = __expf(2.f * x);
                    float s10 = 10.f - 20.f * __builtin_amdgcn_rcpf(1.f + e2);
                    float sraw = m_ ? -10.f : s10;
                    sums[mt][r] += __expf(sraw);
                    lAttn[(mt * 16 + lq4 * 4 + r) * 136 + col] = f2bf(sraw);
                }
        }
        __syncthreads();   // lAttn complete + V staged (drains vmcnt)

        // o += s_raw @ v   (A from lAttn, B from lV)
        #pragma unroll
        for (int ks = 0; ks < 4; ++ks) {
            short8 bfr2 = *(const short8*)&lV[(wv * 16 + l16) * 128 + ks * 32 + lq4 * 8];
            #pragma unroll
            for (int mt = 0; mt < 4; ++mt) {
                short8 af = *(const short8*)&lAttn[(mt * 16 + l16) * 136 + ks * 32 + lq4 * 8];
                o[mt] = __builtin_amdgcn_mfma_f32_16x16x32_bf16(af, bfr2, o[mt], 0, 0, 0);
            }
        }
        // raw-s tile -> sg global bf16 (coalesced 256B per 16-lane group)
        #pragma unroll
        for (int j = 0; j < 4; ++j) {
            int row = j * 16 + (tid >> 4);
            int col = (tid & 15) * 8;
            *(short8*)(sg + ((size_t)bh * SEQ + qbase + row) * SEQ + kbase + col) =
                *(const short8*)&lAttn[row * 136 + col];
        }
        // Vsum partial from the staged V tile (one q-tile per (bh,ksp) does it)
        if (qt == 0) {
            int d = tid >> 2, k0 = (tid & 3) * 32;
            float a = 0.f;
            #pragma unroll
            for (int i = 0; i < 4; ++i) {
                short8 vv = *(const short8*)&lV[d * 128 + k0 + i * 8];
                #pragma unroll
                for (int t = 0; t < 8; ++t) a += bf2f((unsigned short)vv[t]);
            }
            vsum_acc += a;
        }
        __syncthreads();   // lAttn/lV free for next kt
    }

    // Lpart epilogue (pass1 verbatim)
    #pragma unroll
    for (int mt = 0; mt < 4; ++mt)
        #pragma unroll
        for (int r = 0; r < 4; ++r) {
            float v = sums[mt][r];
            v += __shfl_xor(v, 1); v += __shfl_xor(v, 2);
            v += __shfl_xor(v, 4); v += __shfl_xor(v, 8);
            if (l16 == 0) lsumW[wv * 64 + mt * 16 + lq4 * 4 + r] = v;
        }
    __syncthreads();
    if (tid < 64) {
        float v = lsumW[tid] + lsumW[64 + tid] + lsumW[128 + tid] + lsumW[192 + tid];
        Lpart[(size_t)ksp * (8 * SEQ) + (size_t)bh * SEQ + qbase + tid] = v;
    }

    if (qt == 0) {
        float v = vsum_acc;
        v += __shfl_xor(v, 1); v += __shfl_xor(v, 2);
        if ((tid & 3) == 0) vsumPart[ksp * 512 + bh * 64 + (tid >> 2)] = v;
    }

    // raw out-head partials (f32, per k-quarter)
    float* dst = outh2 + (size_t)ksp * (8192 * HDIM);
    #pragma unroll
    for (int mt = 0; mt < 4; ++mt)
        #pragma unroll
        for (int r = 0; r < 4; ++r) {
            int q = qbase + mt * 16 + lq4 * 4 + r;
            int dcol = wv * 16 + l16;
            dst[((size_t)b * SEQ + q) * HDIM + h * DKV + dcol] = o[mt][r];
        }
}

// ---------------------------------------------------------------------------
// k_fin: attnG = bf2f(sg) - L, streaming. 1024 blocks x 256 thr; sg is
// L3-resident (67 MB); write 134 MB coalesced.
__global__ __launch_bounds__(256) void k_fin(
    const unsigned short* __restrict__ sg, const float* __restrict__ Lpart,
    float* __restrict__ attnG) {
    const int bx = blockIdx.x;
    const int bh = bx & 7;
    const int q0 = (bx >> 3) * 16;
    const int tid = threadIdx.x;
    const int row = tid >> 4;
    const size_t ridx = (size_t)bh * SEQ + q0 + row;
    const float Lv = __logf(Lpart[ridx] + Lpart[16384 + ridx] +
                            Lpart[32768 + ridx] + Lpart[49152 + ridx]);
    const unsigned short* srow = sg + ridx * SEQ;
    float* drow = attnG + ridx * SEQ;
    const int c0 = (tid & 15) * 8;
    #pragma unroll
    for (int j = 0; j < 16; ++j) {
        int c = j * 128 + c0;
        short8 v = *(const short8*)(srow + c);
        float4 fa, fb;
        fa.x = bf2f((unsigned short)v[0]) - Lv;
        fa.y = bf2f((unsigned short)v[1]) - Lv;
        fa.z = bf2f((unsigned short)v[2]) - Lv;
        fa.w = bf2f((unsigned short)v[3]) - Lv;
        fb.x = bf2f((unsigned short)v[4]) - Lv;
        fb.y = bf2f((unsigned short)v[5]) - Lv;
        fb.z = bf2f((unsigned short)v[6]) - Lv;
        fb.w = bf2f((unsigned short)v[7]) - Lv;
        *(float4*)(drow + c) = fa;
        *(float4*)(drow + c + 4) = fb;
    }
}

// ---------------------------------------------------------------------------
// k_oproj: out = A @ Wo + bo where A = (sum of 4 raw outh2) - L*Vsum.
// A-stage reads partials coalesced, applies identity, packs bf16 swizzled.
__global__ __launch_bounds__(256) void k_oproj(
    const float* __restrict__ outh2, const unsigned short* __restrict__ Wot,
    const float* __restrict__ bo, const float* __restrict__ Lpart,
    const float* __restrict__ vsumPart, float* __restrict__ outG) {
    __shared__ unsigned short lA2[128 * 128];
    __shared__ unsigned short lB2[128 * 128];
    const int row0 = blockIdx.x * 128, col0 = blockIdx.y * 128;
    const int tid = threadIdx.x, lane = tid & 63, wv = tid >> 6;
    const int l16 = lane & 15, lq4 = lane >> 4;
    const int wr = wv >> 1, wc = wv & 1;

    #pragma unroll
    for (int c = 0; c < 8; ++c) {
        int chunk = wv * 8 + c;
        int row = chunk * 4 + (lane >> 4);
        int gslot = (lane & 15) ^ (row & 7);
        async16((const char*)Wot + ((size_t)(col0 + row)) * 256 + gslot * 16,
                (char*)lB2 + chunk * 1024 + lane * 16);
    }
    {   // A: sum 4 raw partials - L*Vsum, f32 -> bf16, swizzled 8B LDS writes
        const int c16 = tid & 31;                 // 16B f32 chunk (4 cols)
        const int rb = tid >> 5;                  // row 0..7, step 8
        const int hcol = (c16 * 4) >> 6;          // head of this col-chunk
        const int d0 = (c16 * 4) & 63;
        float4 vs;
        {
            float4 v0 = *(const float4*)(vsumPart + hcol * 64 + d0);
            float4 v1 = *(const float4*)(vsumPart + 512 + hcol * 64 + d0);
            float4 v2 = *(const float4*)(vsumPart + 1024 + hcol * 64 + d0);
            float4 v3 = *(const float4*)(vsumPart + 1536 + hcol * 64 + d0);
            vs.x = v0.x + v1.x + v2.x + v3.x;  // NOTE: bh-dependent base added below
            vs.y = v0.y + v1.y + v2.y + v3.y;
            vs.z = v0.z + v1.z + v2.z + v3.z;
            vs.w = v0.w + v1.w + v2.w + v3.w;
        }
        #pragma unroll
        for (int i = 0; i < 16; ++i) {
            int r = rb + i * 8;
            int grow = row0 + r;
            int b_ = grow >> 11, q = grow & 2047;
            int bh = b_ * 2 + hcol;
            // vsum is per-bh: recompute with the bh base (b_ varies only when
            // a block's 128 rows straddle a batch boundary -- they never do:
            // row0 is a multiple of 128 and batches are 2048-row aligned).
            float4 vsb;
            {
                float4 v0 = *(const float4*)(vsumPart + bh * 64 + d0);
                float4 v1 = *(const float4*)(vsumPart + 512 + bh * 64 + d0);
                float4 v2 = *(const float4*)(vsumPart + 1024 + bh * 64 + d0);
                float4 v3 = *(const float4*)(vsumPart + 1536 + bh * 64 + d0);
                vsb.x = v0.x + v1.x + v2.x + v3.x;
                vsb.y = v0.y + v1.y + v2.y + v3.y;
                vsb.z = v0.z + v1.z + v2.z + v3.z;
                vsb.w = v0.w + v1.w + v2.w + v3.w;
            }
            size_t ridx = (size_t)bh * SEQ + q;
            float Lv = __logf(Lpart[ridx] + Lpart[16384 + ridx] +
                              Lpart[32768 + ridx] + Lpart[49152 + ridx]);
            size_t off = (size_t)grow * 128 + c16 * 4;
            float4 a = *(const float4*)(outh2 + off);
            float4 b = *(const float4*)(outh2 + 1048576 + off);
            float4 c = *(const float4*)(outh2 + 2 * 1048576 + off);
            float4 d = *(const float4*)(outh2 + 3 * 1048576 + off);
            float sx = a.x + b.x + c.x + d.x - Lv * vsb.x;
            float sy = a.y + b.y + c.y + d.y - Lv * vsb.y;
            float sz = a.z + b.z + c.z + d.z - Lv * vsb.z;
            float sw = a.w + b.w + c.w + d.w - Lv * vsb.w;
            unsigned p0 = pk2(sx, sy);
            unsigned p1 = pk2(sz, sw);
            unsigned long long pk =
                (unsigned long long)p0 | ((unsigned long long)p1 << 32);
            unsigned bo2 = (unsigned)(r * 256 + c16 * 8) ^ ((unsigned)(r & 7) << 4);
            *(unsigned long long*)((char*)lA2 + bo2) = pk;
        }
        (void)vs;
    }
    __syncthreads();

    f32x4 acc[4][4];
    #pragma unroll
    for (int mt = 0; mt < 4; ++mt)
        #pragma unroll
        for (int nt = 0; nt < 4; ++nt) acc[mt][nt] = f32x4{0.f, 0.f, 0.f, 0.f};

    #pragma unroll
    for (int ks = 0; ks < 4; ++ks) {
        short8 a[4], bfr[4];
        #pragma unroll
        for (int mt = 0; mt < 4; ++mt) {
            int m = wr * 64 + mt * 16 + l16;
            unsigned ao = (unsigned)(m * 256 + ks * 64 + lq4 * 16) ^ ((unsigned)(m & 7) << 4);
            a[mt] = *(const short8*)((const char*)lA2 + ao);
        }
        #pragma unroll
        for (int nt = 0; nt < 4; ++nt) {
            int n = wc * 64 + nt * 16 + l16;
            unsigned bo2 = (unsigned)(n * 256 + ks * 64 + lq4 * 16) ^ ((unsigned)(n & 7) << 4);
            bfr[nt] = *(const short8*)((const char*)lB2 + bo2);
        }
        #pragma unroll
        for (int mt = 0; mt < 4; ++mt)
            #pragma unroll
            for (int nt = 0; nt < 4; ++nt)
                acc[mt][nt] = __builtin_amdgcn_mfma_f32_16x16x32_bf16(
                    a[mt], bfr[nt], acc[mt][nt], 0, 0, 0);
    }

    #pragma unroll
    for (int nt = 0; nt < 4; ++nt) {
        int col = col0 + wc * 64 + nt * 16 + l16;
        float bb = bo[col];
        #pragma unroll
        for (int mt = 0; mt < 4; ++mt)
            #pragma unroll
            for (int r = 0; r < 4; ++r) {
                int row = row0 + wr * 64 + mt * 16 + lq4 * 4 + r;
                outG[(size_t)row * DM + col] = acc[mt][nt][r] + bb;
            }
    }
}

// ---------------------------------------------------------------------------
extern "C" void kernel_launch(void* const* d_in, const int* in_sizes, int n_in,
                              void* d_out, int out_size, void* d_ws, size_t ws_size,
                              hipStream_t stream) {
    (void)in_sizes; (void)n_in; (void)out_size; (void)ws_size;
    const float* Qg = (const float*)d_in[0];
    const float* Kg = (const float*)d_in[1];
    const float* Vg = (const float*)d_in[2];
    const int*   maskg = (const int*)d_in[3];
    const float* Wq = (const float*)d_in[4];
    const float* bq = (const float*)d_in[5];
    const float* Wk = (const float*)d_in[6];
    const float* bk = (const float*)d_in[7];
    const float* Wv = (const float*)d_in[8];
    const float* bv = (const float*)d_in[9];
    const float* Wo = (const float*)d_in[10];
    const float* bo = (const float*)d_in[11];

    char* ws = (char*)d_ws;
    unsigned short* qs    = (unsigned short*)(ws);                   // 2 MB
    unsigned short* kb    = (unsigned short*)(ws + (4  << 20));      // 2 MB
    unsigned short* vt    = (unsigned short*)(ws + (8  << 20));      // 2 MB
    float*          outh2 = (float*)(ws + (12 << 20));               // 16 MB (4 quarters)
    float*          Lpart = (float*)(ws + (28 << 20));               // 256 KB
    float*          vsumP = (float*)(ws + (28 << 20) + 262144);      // 8 KB
    unsigned short* Wqt   = (unsigned short*)(ws + (29 << 20));
    unsigned short* Wkt   = (unsigned short*)((char*)Wqt + 131072);
    unsigned short* Wvt   = (unsigned short*)((char*)Wkt + 131072);
    unsigned short* Wot   = (unsigned short*)((char*)Wvt + 131072);
    unsigned short* sg    = (unsigned short*)(ws + ((size_t)32 << 20)); // 67 MB

    float* outG  = (float*)d_out;
    float* attnG = outG + (size_t)NB * SEQ * DM;

    hipLaunchKernelGGL(k_prep, dim3(64), dim3(256), 0, stream,
                       Wq, Wk, Wv, Wo, Wqt, Wkt, Wvt, Wot);
    hipLaunchKernelGGL(k_proj, dim3(128, 3), dim3(256), 0, stream,
                       Qg, Kg, Vg, Wqt, Wkt, Wvt, bq, bk, bv, qs, kb, vt);
    hipLaunchKernelGGL(k_attn, dim3(1024), dim3(256), 0, stream,
                       qs, kb, vt, maskg, sg, Lpart, vsumP, outh2);
    hipLaunchKernelGGL(k_fin, dim3(1024), dim3(256), 0, stream, sg, Lpart, attnG);
    hipLaunchKernelGGL(k_oproj, dim3(64, 4), dim3(256), 0, stream,
                       outh2, Wot, bo, Lpart, vsumP, outG);
}

// Round 7
// 287.618 us; speedup vs baseline: 1.0450x; 1.0450x over previous
//
#include <hip/hip_runtime.h>

typedef __attribute__((ext_vector_type(8))) short short8;
typedef __attribute__((ext_vector_type(4))) float f32x4;

#define DEVI static __device__ __forceinline__

constexpr int NB   = 4;     // batch
constexpr int NH   = 2;     // heads
constexpr int SEQ  = 2048;  // Lq = Lk
constexpr int DM   = 512;   // d_model
constexpr int DKV  = 64;    // d_k = d_v
constexpr int HDIM = 128;   // NH * DKV

DEVI unsigned short f2bf(float f) {
    union { float f; unsigned u; } v; v.f = f;
    unsigned r = v.u + 0x7FFFu + ((v.u >> 16) & 1u);
    return (unsigned short)(r >> 16);
}
DEVI float bf2f(unsigned short s) {
    union { unsigned u; float f; } v; v.u = ((unsigned)s) << 16; return v.f;
}
DEVI unsigned pk2(float a, float b) {
    return (unsigned)f2bf(a) | ((unsigned)f2bf(b) << 16);
}
// async global->LDS, 16B per lane. LDS dest = wave-uniform base + lane*16.
DEVI void async16(const void* g, void* l) {
    __builtin_amdgcn_global_load_lds(
        (const __attribute__((address_space(1))) unsigned int*)g,
        (__attribute__((address_space(3))) unsigned int*)l, 16, 0, 0);
}

// ---------------------------------------------------------------------------
// k_prep: weights f32 -> bf16 transposed, via LDS tile transpose. (r4 version)
__global__ __launch_bounds__(256) void k_prep(
    const float* __restrict__ Wq, const float* __restrict__ Wk,
    const float* __restrict__ Wv, const float* __restrict__ Wo,
    unsigned short* __restrict__ Wqt, unsigned short* __restrict__ Wkt,
    unsigned short* __restrict__ Wvt, unsigned short* __restrict__ Wot) {
    __shared__ unsigned short T[64][72];          // +8 pad
    const int bid = blockIdx.x, tid = threadIdx.x;
    const float* src; unsigned short* dst; int ss, ds, k0, n0;
    if (bid < 48) {                               // W[512k][128n] -> Wt[128n][512k]
        int m = bid >> 4, t16 = bid & 15;
        src = m == 0 ? Wq : (m == 1 ? Wk : Wv);
        dst = m == 0 ? Wqt : (m == 1 ? Wkt : Wvt);
        ss = 128; ds = 512;
        k0 = (t16 >> 1) * 64; n0 = (t16 & 1) * 64;
    } else {                                      // Wo[128k][512n] -> Wot[512n][128k]
        int t16 = bid - 48;
        src = Wo; dst = Wot; ss = 512; ds = 128;
        k0 = (t16 >> 3) * 64; n0 = (t16 & 7) * 64;
    }
    const int kk = tid >> 4, nn4 = (tid & 15) * 4;
    #pragma unroll
    for (int i = 0; i < 4; ++i) {
        float4 v = *(const float4*)(src + (size_t)(k0 + kk + i * 16) * ss + n0 + nn4);
        T[kk + i * 16][nn4]     = f2bf(v.x);
        T[kk + i * 16][nn4 + 1] = f2bf(v.y);
        T[kk + i * 16][nn4 + 2] = f2bf(v.z);
        T[kk + i * 16][nn4 + 3] = f2bf(v.w);
    }
    __syncthreads();
    const int nn = tid >> 2, kc = (tid & 3) * 16;
    unsigned short tmp[16];
    #pragma unroll
    for (int i = 0; i < 16; ++i) tmp[i] = T[kc + i][nn];
    unsigned short* o = dst + (size_t)(n0 + nn) * ds + k0 + kc;
    *(uint4*)o       = *(uint4*)tmp;
    *(uint4*)(o + 8) = *(uint4*)(tmp + 8);
}

// ---------------------------------------------------------------------------
// k_proj: X[8192,512] @ W[512,128] + b  ->  per-head bf16 layouts. (r0 proven)
__global__ __launch_bounds__(256) void k_proj(
    const float* __restrict__ Qg, const float* __restrict__ Kg, const float* __restrict__ Vg,
    const unsigned short* __restrict__ Wqt, const unsigned short* __restrict__ Wkt,
    const unsigned short* __restrict__ Wvt,
    const float* __restrict__ bq, const float* __restrict__ bk, const float* __restrict__ bv,
    unsigned short* __restrict__ qs, unsigned short* __restrict__ kb,
    unsigned short* __restrict__ vt) {
    __shared__ unsigned short lA[64 * 64];
    __shared__ unsigned short lB[128 * 64];

    const int y = blockIdx.y;
    const float* X = y == 0 ? Qg : (y == 1 ? Kg : Vg);
    const unsigned short* Wt = y == 0 ? Wqt : (y == 1 ? Wkt : Wvt);
    const float* bias = y == 0 ? bq : (y == 1 ? bk : bv);
    const float scal = y == 0 ? 0.125f : 1.0f;   // fold 1/sqrt(dk) into q
    const int row0 = blockIdx.x * 64;
    const int tid = threadIdx.x, lane = tid & 63, wv = tid >> 6;
    const int l16 = lane & 15, lq4 = lane >> 4;
    const int wr = wv >> 1, wc = wv & 1;

    f32x4 acc[2][4];
    #pragma unroll
    for (int i = 0; i < 2; ++i)
        #pragma unroll
        for (int j = 0; j < 4; ++j) acc[i][j] = f32x4{0.f, 0.f, 0.f, 0.f};

    const int arow = tid >> 2, ac0 = (tid & 3) * 16;

    for (int kc = 0; kc < 8; ++kc) {
        {
            const float* src = X + (size_t)(row0 + arow) * DM + kc * 64 + ac0;
            unsigned short* dst = &lA[arow * 64 + ac0];
            #pragma unroll
            for (int i = 0; i < 4; ++i) {
                float4 v = *(const float4*)(src + 4 * i);
                unsigned p0 = (unsigned)f2bf(v.x) | ((unsigned)f2bf(v.y) << 16);
                unsigned p1 = (unsigned)f2bf(v.z) | ((unsigned)f2bf(v.w) << 16);
                *(unsigned*)(dst + 4 * i) = p0;
                *(unsigned*)(dst + 4 * i + 2) = p1;
            }
        }
        #pragma unroll
        for (int c = 0; c < 4; ++c) {
            int chunk = wv * 4 + c;
            int n = chunk * 8 + (lane >> 3);
            int kpart = (lane & 7) * 8;
            const void* g = (const char*)Wt + ((size_t)n * DM + kc * 64 + kpart) * 2;
            void* l = (char*)lB + chunk * 1024 + lane * 16;
            async16(g, l);
        }
        __syncthreads();

        #pragma unroll
        for (int ks = 0; ks < 2; ++ks) {
            short8 a[2], b[4];
            #pragma unroll
            for (int mt = 0; mt < 2; ++mt) {
                int m = wr * 32 + mt * 16 + l16;
                a[mt] = *(const short8*)&lA[m * 64 + ks * 32 + lq4 * 8];
            }
            #pragma unroll
            for (int nt = 0; nt < 4; ++nt) {
                int n = wc * 64 + nt * 16 + l16;
                b[nt] = *(const short8*)&lB[n * 64 + ks * 32 + lq4 * 8];
            }
            #pragma unroll
            for (int mt = 0; mt < 2; ++mt)
                #pragma unroll
                for (int nt = 0; nt < 4; ++nt)
                    acc[mt][nt] = __builtin_amdgcn_mfma_f32_16x16x32_bf16(
                        a[mt], b[nt], acc[mt][nt], 0, 0, 0);
        }
        __syncthreads();
    }

    if (y < 2) {
        unsigned short* dstp = (y == 0) ? qs : kb;
        #pragma unroll
        for (int mt = 0; mt < 2; ++mt)
            #pragma unroll
            for (int nt = 0; nt < 4; ++nt) {
                int col = wc * 64 + nt * 16 + l16;
                float bb = bias[col];
                int h = col >> 6, d = col & 63;
                #pragma unroll
                for (int r = 0; r < 4; ++r) {
                    int row = row0 + wr * 32 + mt * 16 + lq4 * 4 + r;
                    int b = row >> 11, pos = row & 2047;
                    float val = (acc[mt][nt][r] + bb) * scal;
                    dstp[((size_t)(b * NH + h) * SEQ + pos) * DKV + d] = f2bf(val);
                }
            }
    } else {
        #pragma unroll
        for (int mt = 0; mt < 2; ++mt)
            #pragma unroll
            for (int nt = 0; nt < 4; ++nt) {
                int col = wc * 64 + nt * 16 + l16;
                float bb = bias[col];
                #pragma unroll
                for (int r = 0; r < 4; ++r) {
                    int mrow = wr * 32 + mt * 16 + lq4 * 4 + r;
                    lB[col * 64 + mrow] = f2bf(acc[mt][nt][r] + bb);
                }
            }
        __syncthreads();
        int c = tid >> 1, mp = (tid & 1) * 32;
        int b = row0 >> 11, kpos0 = row0 & 2047;
        int h = c >> 6, d = c & 63;
        unsigned short* dst = vt + ((size_t)(b * NH + h) * DKV + d) * SEQ + kpos0 + mp;
        const unsigned short* srcl = &lB[c * 64 + mp];
        #pragma unroll
        for (int i = 0; i < 4; ++i)
            *(uint4*)(dst + 8 * i) = *(const uint4*)(srcl + 8 * i);
    }
}

// ---------------------------------------------------------------------------
// k_attn: ONE kernel per (bh, 16-row q-tile), FULL k range. Scores live in
// registers (8 x f32x4 per lane), so L = log(sum exp) is block-local: no
// second QK pass, no Lpart/outh2/sg global round-trips.
//   phase 1: per-wave QK (128 cols each) -> tanh/mask -> sraw regs + exp-sums
//   phase 2: cross-wave sums -> L (16 rows)
//   phase 3: a = sraw - L -> lAttn (bf16, XOR-swizzled)
//   phase 4: coalesced attnG f32 sweep from lAttn (134 MB, the kernel's floor)
//   phase 5: PV per wave over its own 128-k slice (A from lAttn, B=v^T from
//            L2), cross-wave reduce via oBuf LDS -> outh bf16 direct.
// grid 1024 = 8 bh (XCD-pinned) * 128 q-tiles; 1024 threads = 16 waves.
__global__ __launch_bounds__(1024, 1) void k_attn(
    const unsigned short* __restrict__ qs, const unsigned short* __restrict__ kb,
    const unsigned short* __restrict__ vt, const int* __restrict__ maskg,
    float* __restrict__ attnG, unsigned short* __restrict__ outh) {
    __shared__ unsigned short lAttn[16 * 2048];   // 64 KB, byte ^= (row&7)<<4
    __shared__ float oBuf[16][16][64];            // 64 KB PV partials
    __shared__ float lsum[16][16];
    __shared__ float lL[16];

    const int bx = blockIdx.x;
    const int bh = bx & 7;                        // XCD-pinned
    const int qt = bx >> 3;                       // 0..127
    const int qbase = qt * 16;
    const int b = bh >> 1, h = bh & 1;
    const int tid = threadIdx.x, lane = tid & 63, wv = tid >> 6;  // 16 waves
    const int l16 = lane & 15, lq4 = lane >> 4;

    // Q fragments: rows qbase + l16 (q pre-scaled by 1/8)
    const unsigned short* qrow =
        qs + ((size_t)bh * SEQ + qbase + l16) * DKV + lq4 * 8;
    const short8 aq0 = *(const short8*)qrow;
    const short8 aq1 = *(const short8*)(qrow + 32);

    const unsigned short* kB = kb + (size_t)bh * SEQ * DKV;
    const int* mB = maskg + b * SEQ;

    // phase 1: QK over this wave's 128 cols; scores stay in registers
    f32x4 sraw[8];
    float sums[4] = {0.f, 0.f, 0.f, 0.f};
    #pragma unroll
    for (int j = 0; j < 8; ++j) {
        int n = wv * 128 + j * 16 + l16;
        const unsigned short* p = kB + (size_t)n * DKV + lq4 * 8;
        short8 b0 = *(const short8*)p;
        short8 b1 = *(const short8*)(p + 32);
        int mv = mB[n];
        f32x4 acc = f32x4{0.f, 0.f, 0.f, 0.f};
        acc = __builtin_amdgcn_mfma_f32_16x16x32_bf16(aq0, b0, acc, 0, 0, 0);
        acc = __builtin_amdgcn_mfma_f32_16x16x32_bf16(aq1, b1, acc, 0, 0, 0);
        #pragma unroll
        for (int r = 0; r < 4; ++r) {
            float x = acc[r];                     // q.k / 8
            float e2 = __expf(2.f * x);
            float s10 = 10.f - 20.f * __builtin_amdgcn_rcpf(1.f + e2);
            float s = mv ? -10.f : s10;
            sums[r] += __expf(s);
            sraw[j][r] = s;
        }
    }

    // phase 2: row sums -> L
    #pragma unroll
    for (int r = 0; r < 4; ++r) {
        float v = sums[r];
        v += __shfl_xor(v, 1); v += __shfl_xor(v, 2);
        v += __shfl_xor(v, 4); v += __shfl_xor(v, 8);
        if (l16 == 0) lsum[wv][lq4 * 4 + r] = v;
    }
    __syncthreads();
    if (tid < 16) {
        float t = 0.f;
        #pragma unroll
        for (int w = 0; w < 16; ++w) t += lsum[w][tid];
        lL[tid] = __logf(t);
    }
    __syncthreads();

    // phase 3: a = sraw - L -> lAttn (bf16, swizzled)
    {
        float Lr[4];
        #pragma unroll
        for (int r = 0; r < 4; ++r) Lr[r] = lL[lq4 * 4 + r];
        #pragma unroll
        for (int j = 0; j < 8; ++j) {
            int col = wv * 128 + j * 16 + l16;
            #pragma unroll
            for (int r = 0; r < 4; ++r) {
                int row = lq4 * 4 + r;
                float a = sraw[j][r] - Lr[r];
                unsigned bo = (unsigned)(row * 4096 + col * 2) ^ ((unsigned)(row & 7) << 4);
                *(unsigned short*)((char*)lAttn + bo) = f2bf(a);
            }
        }
    }
    __syncthreads();

    // phase 4: attnG f32 sweep, fully coalesced (2KB per 64-thread row-group)
    {
        const int row = tid >> 6;
        const int c0 = (tid & 63) * 8;
        float* drow = attnG + ((size_t)bh * SEQ + qbase + row) * SEQ;
        const unsigned rbase = (unsigned)(row * 4096);
        const unsigned rxor = (unsigned)(row & 7) << 4;
        #pragma unroll
        for (int j = 0; j < 4; ++j) {
            int c = c0 + j * 512;
            short8 v = *(const short8*)((const char*)lAttn + ((rbase + (unsigned)(c * 2)) ^ rxor));
            float4 fa, fb;
            fa.x = bf2f((unsigned short)v[0]); fa.y = bf2f((unsigned short)v[1]);
            fa.z = bf2f((unsigned short)v[2]); fa.w = bf2f((unsigned short)v[3]);
            fb.x = bf2f((unsigned short)v[4]); fb.y = bf2f((unsigned short)v[5]);
            fb.z = bf2f((unsigned short)v[6]); fb.w = bf2f((unsigned short)v[7]);
            *(float4*)(drow + c) = fa;
            *(float4*)(drow + c + 4) = fb;
        }
    }

    // phase 5: PV over this wave's 128-k slice; B = v^T rows direct from L2
    {
        const int k0 = wv * 128;
        f32x4 o[4];
        #pragma unroll
        for (int nt = 0; nt < 4; ++nt) o[nt] = f32x4{0.f, 0.f, 0.f, 0.f};
        const unsigned abase = (unsigned)(l16 * 4096 + k0 * 2);
        const unsigned axor = (unsigned)(l16 & 7) << 4;
        #pragma unroll
        for (int ks = 0; ks < 4; ++ks) {
            short8 af = *(const short8*)((const char*)lAttn +
                          ((abase + (unsigned)(ks * 64 + lq4 * 16)) ^ axor));
            #pragma unroll
            for (int nt = 0; nt < 4; ++nt) {
                const unsigned short* vp =
                    vt + ((size_t)bh * DKV + nt * 16 + l16) * SEQ + k0 + ks * 32 + lq4 * 8;
                short8 vf = *(const short8*)vp;
                o[nt] = __builtin_amdgcn_mfma_f32_16x16x32_bf16(af, vf, o[nt], 0, 0, 0);
            }
        }
        #pragma unroll
        for (int nt = 0; nt < 4; ++nt)
            #pragma unroll
            for (int r = 0; r < 4; ++r)
                oBuf[wv][lq4 * 4 + r][nt * 16 + l16] = o[nt][r];
    }
    __syncthreads();

    // cross-wave PV reduce -> outh bf16 (thread t owns (row, d))
    {
        const int row = tid >> 6, d = tid & 63;
        float s = 0.f;
        #pragma unroll
        for (int w = 0; w < 16; ++w) s += oBuf[w][row][d];
        outh[((size_t)b * SEQ + qbase + row) * HDIM + h * DKV + d] = f2bf(s);
    }
}

// ---------------------------------------------------------------------------
// k_oproj: out = outh[8192,128] @ Wo[128,512] + bo.  grid (64, 4).
// Staging pre-swizzled at the global source; reads swizzled -> conflict-free.
__global__ __launch_bounds__(256) void k_oproj(
    const unsigned short* __restrict__ outh, const unsigned short* __restrict__ Wot,
    const float* __restrict__ bo, float* __restrict__ outG) {
    __shared__ unsigned short lA2[128 * 128];
    __shared__ unsigned short lB2[128 * 128];
    const int row0 = blockIdx.x * 128, col0 = blockIdx.y * 128;
    const int tid = threadIdx.x, lane = tid & 63, wv = tid >> 6;
    const int l16 = lane & 15, lq4 = lane >> 4;
    const int wr = wv >> 1, wc = wv & 1;

    #pragma unroll
    for (int c = 0; c < 8; ++c) {
        int chunk = wv * 8 + c;
        int row = chunk * 4 + (lane >> 4);
        int gslot = (lane & 15) ^ (row & 7);
        async16((const char*)outh + ((size_t)(row0 + row)) * 256 + gslot * 16,
                (char*)lA2 + chunk * 1024 + lane * 16);
    }
    #pragma unroll
    for (int c = 0; c < 8; ++c) {
        int chunk = wv * 8 + c;
        int row = chunk * 4 + (lane >> 4);
        int gslot = (lane & 15) ^ (row & 7);
        async16((const char*)Wot + ((size_t)(col0 + row)) * 256 + gslot * 16,
                (char*)lB2 + chunk * 1024 + lane * 16);
    }
    __syncthreads();

    f32x4 acc[4][4];
    #pragma unroll
    for (int mt = 0; mt < 4; ++mt)
        #pragma unroll
        for (int nt = 0; nt < 4; ++nt) acc[mt][nt] = f32x4{0.f, 0.f, 0.f, 0.f};

    #pragma unroll
    for (int ks = 0; ks < 4; ++ks) {
        short8 a[4], bfr[4];
        #pragma unroll
        for (int mt = 0; mt < 4; ++mt) {
            int m = wr * 64 + mt * 16 + l16;
            unsigned ao = (unsigned)(m * 256 + ks * 64 + lq4 * 16) ^ ((unsigned)(m & 7) << 4);
            a[mt] = *(const short8*)((const char*)lA2 + ao);
        }
        #pragma unroll
        for (int nt = 0; nt < 4; ++nt) {
            int n = wc * 64 + nt * 16 + l16;
            unsigned bo2 = (unsigned)(n * 256 + ks * 64 + lq4 * 16) ^ ((unsigned)(n & 7) << 4);
            bfr[nt] = *(const short8*)((const char*)lB2 + bo2);
        }
        #pragma unroll
        for (int mt = 0; mt < 4; ++mt)
            #pragma unroll
            for (int nt = 0; nt < 4; ++nt)
                acc[mt][nt] = __builtin_amdgcn_mfma_f32_16x16x32_bf16(
                    a[mt], bfr[nt], acc[mt][nt], 0, 0, 0);
    }

    #pragma unroll
    for (int nt = 0; nt < 4; ++nt) {
        int col = col0 + wc * 64 + nt * 16 + l16;
        float bb = bo[col];
        #pragma unroll
        for (int mt = 0; mt < 4; ++mt)
            #pragma unroll
            for (int r = 0; r < 4; ++r) {
                int row = row0 + wr * 64 + mt * 16 + lq4 * 4 + r;
                outG[(size_t)row * DM + col] = acc[mt][nt][r] + bb;
            }
    }
}

// ---------------------------------------------------------------------------
extern "C" void kernel_launch(void* const* d_in, const int* in_sizes, int n_in,
                              void* d_out, int out_size, void* d_ws, size_t ws_size,
                              hipStream_t stream) {
    (void)in_sizes; (void)n_in; (void)out_size; (void)ws_size;
    const float* Qg = (const float*)d_in[0];
    const float* Kg = (const float*)d_in[1];
    const float* Vg = (const float*)d_in[2];
    const int*   maskg = (const int*)d_in[3];
    const float* Wq = (const float*)d_in[4];
    const float* bq = (const float*)d_in[5];
    const float* Wk = (const float*)d_in[6];
    const float* bk = (const float*)d_in[7];
    const float* Wv = (const float*)d_in[8];
    const float* bv = (const float*)d_in[9];
    const float* Wo = (const float*)d_in[10];
    const float* bo = (const float*)d_in[11];

    char* ws = (char*)d_ws;
    unsigned short* qs   = (unsigned short*)(ws);                    // 2 MB
    unsigned short* kb   = (unsigned short*)(ws + (4  << 20));       // 2 MB
    unsigned short* vt   = (unsigned short*)(ws + (8  << 20));       // 2 MB
    unsigned short* outh = (unsigned short*)(ws + (12 << 20));       // 2 MB
    unsigned short* Wqt  = (unsigned short*)(ws + (16 << 20));
    unsigned short* Wkt  = (unsigned short*)((char*)Wqt + 131072);
    unsigned short* Wvt  = (unsigned short*)((char*)Wkt + 131072);
    unsigned short* Wot  = (unsigned short*)((char*)Wvt + 131072);

    float* outG  = (float*)d_out;
    float* attnG = outG + (size_t)NB * SEQ * DM;

    hipLaunchKernelGGL(k_prep, dim3(64), dim3(256), 0, stream,
                       Wq, Wk, Wv, Wo, Wqt, Wkt, Wvt, Wot);
    hipLaunchKernelGGL(k_proj, dim3(128, 3), dim3(256), 0, stream,
                       Qg, Kg, Vg, Wqt, Wkt, Wvt, bq, bk, bv, qs, kb, vt);
    hipLaunchKernelGGL(k_attn, dim3(1024), dim3(1024), 0, stream,
                       qs, kb, vt, maskg, attnG, outh);
    hipLaunchKernelGGL(k_oproj, dim3(64, 4), dim3(256), 0, stream, outh, Wot, bo, outG);
}